// Round 1
// baseline (68.653 us; speedup 1.0000x reference)
//
#include <hip/hip_runtime.h>

// Match XLA's elementwise f32 exactly: no FMA contraction anywhere in this file.
// (HIP default is -ffp-contract=fast-honor-pragmas, so this pragma is honored.)
#pragma clang fp contract(off)

#define N_BOX   10647
#define N_CLS   80
#define ROW     85
#define CONF_T  0.8f
#define NMS_T   0.4f
#define NEGV    -1000000000.0f
#define CAP     4096      // max valid boxes stored (expected ~2130)
#define KMAX    512       // max boxes per class (expected ~27)
#define OUT_N   3000
#define SORT_N  4096

struct Rec { float x1, y1, x2, y2, score, conf; int idx, cls; };

__global__ void k_init(int* counters) {
    counters[0] = 0;   // valid count
    counters[1] = 0;   // survivor count
}

// Stage 1: batch 0 only. Filter obj>=0.8, compute cls max/argmax, xyxy box.
__global__ __launch_bounds__(256) void k_stage1(const float* __restrict__ det,
                                                Rec* __restrict__ recs,
                                                int* __restrict__ counters) {
    int i = blockIdx.x * blockDim.x + threadIdx.x;
    if (i >= N_BOX) return;
    const float* p = det + (size_t)i * ROW;   // batch 0 rows
    float obj = p[4];
    if (!(obj >= CONF_T)) return;

    float cx = p[0], cy = p[1], w = p[2], h = p[3];
    float hw = w / 2.0f, hh = h / 2.0f;
    float x1 = cx - hw, y1 = cy - hh, x2 = cx + hw, y2 = cy + hh;

    // max / first-argmax over 80 classes (strict > keeps first occurrence,
    // matching jnp.argmax)
    float best = p[5]; int bid = 0;
    for (int c = 1; c < N_CLS; ++c) {
        float v = p[5 + c];
        if (v > best) { best = v; bid = c; }
    }
    float score = obj * best;

    int pos = atomicAdd(&counters[0], 1);
    if (pos < CAP) {
        Rec r; r.x1 = x1; r.y1 = y1; r.x2 = x2; r.y2 = y2;
        r.score = score; r.conf = best; r.idx = i; r.cls = bid;
        recs[pos] = r;
    }
}

// Stage 2: one block per class. Gather class boxes, sort by (score desc, idx asc)
// = stable argsort(-score), then greedy NMS with the reference's exact IoU.
__global__ __launch_bounds__(256) void k_nms(const Rec* __restrict__ recs,
                                             const int* __restrict__ counters,
                                             float* __restrict__ surv,
                                             int* __restrict__ surv_cnt) {
    const int c = blockIdx.x;
    const int tid = threadIdx.x;
    const int bd  = blockDim.x;

    __shared__ int cnt, nkeep, base;
    __shared__ float rx1[KMAX], ry1[KMAX], rx2[KMAX], ry2[KMAX], rsc[KMAX], rcf[KMAX];
    __shared__ int   ridx[KMAX];
    __shared__ float sx1[KMAX], sy1[KMAX], sx2[KMAX], sy2[KMAX], scf[KMAX];
    __shared__ unsigned char alive[KMAX];
    __shared__ float keepc[KMAX];

    if (tid == 0) { cnt = 0; nkeep = 0; }
    __syncthreads();

    int vc = counters[0]; if (vc > CAP) vc = CAP;
    for (int i = tid; i < vc; i += bd) {
        Rec r = recs[i];
        if (r.cls == c) {
            int p = atomicAdd(&cnt, 1);
            if (p < KMAX) {
                rx1[p] = r.x1; ry1[p] = r.y1; rx2[p] = r.x2; ry2[p] = r.y2;
                rsc[p] = r.score; rcf[p] = r.conf; ridx[p] = r.idx;
            }
        }
    }
    __syncthreads();
    int k = cnt; if (k > KMAX) k = KMAX;

    // rank sort: rank = #{j : score[j] > score[i]  or  (==, idx[j] < idx[i])}
    for (int i = tid; i < k; i += bd) {
        float s = rsc[i]; int id = ridx[i]; int r = 0;
        for (int j = 0; j < k; ++j) {
            float sj = rsc[j];
            r += (sj > s) || (sj == s && ridx[j] < id);
        }
        sx1[r] = rx1[i]; sy1[r] = ry1[i]; sx2[r] = rx2[i]; sy2[r] = ry2[i];
        scf[r] = rcf[i];
        alive[r] = 1;
    }
    __syncthreads();

    // greedy NMS
    for (int i = 0; i < k; ++i) {
        __syncthreads();
        bool a = (alive[i] != 0);
        __syncthreads();              // all reads of alive[i] before thread0 clears it
        if (a) {
            if (tid == 0) { keepc[nkeep++] = scf[i]; alive[i] = 0; }
            float bx1 = sx1[i], by1 = sy1[i], bx2 = sx2[i], by2 = sy2[i];
            float a1 = ((bx2 - bx1) + 1.0f) * ((by2 - by1) + 1.0f);
            for (int j = i + 1 + tid; j < k; j += bd) {
                if (!alive[j]) continue;
                float ix1 = fmaxf(bx1, sx1[j]);
                float iy1 = fmaxf(by1, sy1[j]);
                float ix2 = fminf(bx2, sx2[j]);
                float iy2 = fminf(by2, sy2[j]);
                float iw = fmaxf((ix2 - ix1) + 1.0f, 0.0f);
                float ih = fmaxf((iy2 - iy1) + 1.0f, 0.0f);
                float inter = iw * ih;
                float a2 = ((sx2[j] - sx1[j]) + 1.0f) * ((sy2[j] - sy1[j]) + 1.0f);
                float den = ((a1 + a2) - inter) + 1e-16f;
                float iou = inter / den;
                if (iou > NMS_T) alive[j] = 0;
            }
        }
    }
    __syncthreads();

    if (tid == 0) base = atomicAdd(surv_cnt, nkeep);
    __syncthreads();
    int nb = nkeep, b = base;
    for (int i = tid; i < nb; i += bd) {
        int o = b + i;
        if (o < SORT_N) surv[o] = keepc[i];
    }
}

// Stage 3: single-block bitonic sort of 4096 (picked confs padded with NEG),
// write top 3000 descending.
__global__ __launch_bounds__(1024) void k_sort(const float* __restrict__ surv,
                                               const int* __restrict__ counters,
                                               float* __restrict__ out) {
    __shared__ float s[SORT_N];
    int tid = threadIdx.x;
    int m = counters[1]; if (m > SORT_N) m = SORT_N;
    for (int i = tid; i < SORT_N; i += blockDim.x) s[i] = (i < m) ? surv[i] : NEGV;
    __syncthreads();
    for (int size = 2; size <= SORT_N; size <<= 1) {
        for (int stride = size >> 1; stride > 0; stride >>= 1) {
            for (int t = tid; t < SORT_N / 2; t += blockDim.x) {
                int i = ((t & ~(stride - 1)) << 1) | (t & (stride - 1));
                int j = i | stride;
                bool up = ((i & size) == 0);
                float a = s[i], b = s[j];
                if ((a > b) == up) { s[i] = b; s[j] = a; }
            }
            __syncthreads();
        }
    }
    // ascending in s -> emit descending
    for (int t = tid; t < OUT_N; t += blockDim.x) out[t] = s[SORT_N - 1 - t];
}

extern "C" void kernel_launch(void* const* d_in, const int* in_sizes, int n_in,
                              void* d_out, int out_size, void* d_ws, size_t ws_size,
                              hipStream_t stream) {
    const float* det = (const float*)d_in[0];
    float* out = (float*)d_out;

    int*  counters = (int*)d_ws;                                   // 2 ints
    Rec*  recs     = (Rec*)((char*)d_ws + 64);                     // CAP * 32B
    float* surv    = (float*)((char*)d_ws + 64 + CAP * sizeof(Rec)); // SORT_N floats

    hipLaunchKernelGGL(k_init,   dim3(1), dim3(1), 0, stream, counters);
    hipLaunchKernelGGL(k_stage1, dim3((N_BOX + 255) / 256), dim3(256), 0, stream,
                       det, recs, counters);
    hipLaunchKernelGGL(k_nms,    dim3(N_CLS), dim3(256), 0, stream,
                       recs, counters, surv, counters + 1);
    hipLaunchKernelGGL(k_sort,   dim3(1), dim3(1024), 0, stream,
                       surv, counters, out);
}